// Round 8
// baseline (1751.971 us; speedup 1.0000x reference)
//
#include <hip/hip_runtime.h>
#include <hip/hip_bf16.h>
#include <cstdint>
#include <cstddef>

typedef __bf16 bf16x8 __attribute__((ext_vector_type(8)));
typedef __bf16 bf16x4 __attribute__((ext_vector_type(4)));
typedef __bf16 bf16x2 __attribute__((ext_vector_type(2)));
typedef float  f32x4  __attribute__((ext_vector_type(4)));
typedef float  f32x2  __attribute__((ext_vector_type(2)));

#define T_SEQ 2048
#define CDIM  2048
#define NH    16
#define NG    4
#define DH    128
#define NCHUNK 32   // T / 64

__device__ __forceinline__ void gl_lds16(const __bf16* g, __bf16* l) {
  __builtin_amdgcn_global_load_lds(
      (const __attribute__((address_space(1))) void*)g,
      (__attribute__((address_space(3))) void*)l, 16, 0, 0);
}

// ---------------- fused preprocess: cast x->bf16, transpose+cast 3 weights ----------------
__global__ __launch_bounds__(256) void pre_kernel(
    const float* __restrict__ x, const float* __restrict__ Wr,
    const float* __restrict__ Wg, const float* __restrict__ Wp,
    __bf16* __restrict__ xb, __bf16* __restrict__ wtb, __bf16* __restrict__ wpb) {
  __shared__ __bf16 tile[64][68];
  int bid = blockIdx.x;
  int tid = threadIdx.x;
  if (bid < 2048) {   // cast x (4M elements)
    size_t i = ((size_t)bid * 256 + tid) * 8;
    f32x4 a = *(const f32x4*)(x + i);
    f32x4 b = *(const f32x4*)(x + i + 4);
    bf16x8 o;
#pragma unroll
    for (int j = 0; j < 4; ++j) { o[j] = (__bf16)a[j]; o[4 + j] = (__bf16)b[j]; }
    *(bf16x8*)(xb + i) = o;
    return;
  }
  int rel = bid - 2048;
  const float* W; __bf16* Wt; int N;
  if (rel < 1536)      { W = Wr; Wt = wtb;                        N = 3072; }
  else if (rel < 2560) { W = Wg; Wt = wtb + (size_t)3072 * CDIM;  N = 2048; rel -= 1536; }
  else                 { W = Wp; Wt = wpb;                        N = 2048; rel -= 2560; }
  const int K = 2048;
  int k0 = (rel & 31) * 64, n0 = (rel >> 5) * 64;
  int c4 = (tid & 15) * 4, r = tid >> 4;
#pragma unroll
  for (int rr = 0; rr < 4; ++rr) {
    int row = r + rr * 16;
    f32x4 v = *(const f32x4*)(W + (size_t)(k0 + row) * N + n0 + c4);
#pragma unroll
    for (int j = 0; j < 4; ++j) tile[row][c4 + j] = (__bf16)v[j];
  }
  __syncthreads();
  int n = tid >> 2, seg = tid & 3;
  __bf16 vals[16];
#pragma unroll
  for (int j = 0; j < 16; ++j) vals[j] = tile[seg * 16 + j][n];
  __bf16* dst = Wt + (size_t)(n0 + n) * K + k0 + seg * 16;
  *(bf16x8*)(dst)     = *(bf16x8*)(&vals[0]);
  *(bf16x8*)(dst + 8) = *(bf16x8*)(&vals[8]);
}

// ---- fused: RoPE q,k scatter (0..2047) | v transpose (2048..2175) | k-rope-transpose (2176..2303)
__global__ __launch_bounds__(256) void ropekt_kernel(const float* __restrict__ qkv,
    const float* __restrict__ cosb, const float* __restrict__ sinb,
    __bf16* __restrict__ qb, __bf16* __restrict__ kb,
    __bf16* __restrict__ vtb, __bf16* __restrict__ ktb) {
  __shared__ __bf16 vt[64][136];
  int bid = blockIdx.x;
  int tid = threadIdx.x;
  if (bid < 2048) {     // RoPE scatter q,k -> [head][t][d]
    int t = bid;
    int w = tid >> 6, l = tid & 63;
    float c = cosb[t * 64 + l], s = sinb[t * 64 + l];
#pragma unroll
    for (int it = 0; it < 5; ++it) {
      int slot = w + it * 4;
      int g = slot / 5, j = slot % 5;
      const float* src = qkv + (size_t)t * 3072 + g * 768 + j * 128;
      f32x2 xv = *(const f32x2*)(src + 2 * l);
      bf16x2 o;
      o[0] = (__bf16)(xv[0] * c - xv[1] * s);
      o[1] = (__bf16)(xv[0] * s + xv[1] * c);
      __bf16* dst = (j < 4) ? (qb + ((size_t)(g * 4 + j) * T_SEQ + t) * DH)
                            : (kb + ((size_t)g * T_SEQ + t) * DH);
      *(bf16x2*)(dst + 2 * l) = o;
    }
    return;
  }
  if (bid < 2176) {     // v transpose: qkv v-section [t][d] f32 -> vtb[g][d][t] bf16
    int rel = bid - 2048;
    int g = rel >> 5, t0 = (rel & 31) * 64;
#pragma unroll
    for (int it = 0; it < 8; ++it) {
      int q = it * 256 + tid;
      int tt = q >> 5, dq = q & 31;
      f32x4 v = *(const f32x4*)(qkv + (size_t)(t0 + tt) * 3072 + g * 768 + 640 + dq * 4);
#pragma unroll
      for (int j = 0; j < 4; ++j) vt[tt][dq * 4 + j] = (__bf16)v[j];
    }
    __syncthreads();
    int d = tid >> 1, half = tid & 1;
    __bf16 outv[32];
#pragma unroll
    for (int j = 0; j < 32; ++j) outv[j] = vt[half * 32 + j][d];
    __bf16* dst = vtb + ((size_t)g * DH + d) * T_SEQ + t0 + half * 32;
#pragma unroll
    for (int q4 = 0; q4 < 4; ++q4) *(bf16x8*)(dst + q4 * 8) = *(bf16x8*)(&outv[q4 * 8]);
    return;
  }
  // k-rope-transpose: qkv k-section [t][d] f32 --RoPE--> ktb[g][d][t] bf16
  int rel = bid - 2176;
  int g = rel >> 5, t0 = (rel & 31) * 64;
#pragma unroll
  for (int it = 0; it < 8; ++it) {
    int q = it * 256 + tid;
    int tt = q >> 5, dq = q & 31;
    int t = t0 + tt;
    f32x4 v = *(const f32x4*)(qkv + (size_t)t * 3072 + g * 768 + 512 + dq * 4);
    float c0 = cosb[t * 64 + dq * 2],     s0 = sinb[t * 64 + dq * 2];
    float c1 = cosb[t * 64 + dq * 2 + 1], s1 = sinb[t * 64 + dq * 2 + 1];
    vt[tt][dq * 4 + 0] = (__bf16)(v[0] * c0 - v[1] * s0);
    vt[tt][dq * 4 + 1] = (__bf16)(v[0] * s0 + v[1] * c0);
    vt[tt][dq * 4 + 2] = (__bf16)(v[2] * c1 - v[3] * s1);
    vt[tt][dq * 4 + 3] = (__bf16)(v[2] * s1 + v[3] * c1);
  }
  __syncthreads();
  int d = tid >> 1, half = tid & 1;
  __bf16 outv[32];
#pragma unroll
  for (int j = 0; j < 32; ++j) outv[j] = vt[half * 32 + j][d];
  __bf16* dst = ktb + ((size_t)g * DH + d) * T_SEQ + t0 + half * 32;
#pragma unroll
  for (int q4 = 0; q4 < 4; ++q4) *(bf16x8*)(dst + q4 * 8) = *(bf16x8*)(&outv[q4 * 8]);
}

// ---------------- fused U+scan: per (h, d2-slice, d1-half) block, sequential over chunks ----
__global__ __launch_bounds__(256) void uscan_kernel(const __bf16* __restrict__ vtb,
                                                    const __bf16* __restrict__ ktb,
                                                    __bf16* __restrict__ St) {
  int bid = blockIdx.x;                 // NH*8*2 = 256
  int h = bid >> 4, m = (bid >> 1) & 7, half = bid & 1;
  int g = h >> 2;
  int tid = threadIdx.x, w = tid >> 6, l = tid & 63, lr = l & 15, lg = l >> 4;
  int jf = half * 4 + w;                // d1 block 0..7
  float l2g = log2f(1.0f - exp2f(-5.0f - (float)h));
  float ginv = exp2f(-l2g);             // 1/gamma
  float df   = exp2f(l2g * 64.0f);      // gamma^64
  float wk[2];
#pragma unroll
  for (int kk = 0; kk < 2; ++kk) wk[kk] = exp2f(l2g * (float)(64 - (kk * 32 + lg * 8)));
  const __bf16* vrow = vtb + ((size_t)g * DH + m * 16 + lr) * T_SEQ;
  const __bf16* krow = ktb + ((size_t)g * DH + jf * 16 + lr) * T_SEQ;
  f32x4 S = {0.f, 0.f, 0.f, 0.f};
  for (int c = 0; c < NCHUNK; ++c) {
    f32x4 u = {0.f, 0.f, 0.f, 0.f};
#pragma unroll
    for (int kk = 0; kk < 2; ++kk) {
      int j0 = c * 64 + kk * 32 + lg * 8;
      bf16x8 av = *(const bf16x8*)(vrow + j0);
      bf16x8 bv = *(const bf16x8*)(krow + j0);
      bf16x8 aw;
      float wj = wk[kk];
#pragma unroll
      for (int jj = 0; jj < 8; ++jj) { aw[jj] = (__bf16)((float)av[jj] * wj); wj *= ginv; }
      u = __builtin_amdgcn_mfma_f32_16x16x32_bf16(aw, bv, u, 0, 0, 0);
    }
    __bf16* out = St + ((size_t)(h * NCHUNK + c) * 128 + m * 16 + lg * 4) * 128 + jf * 16 + lr;
#pragma unroll
    for (int r = 0; r < 4; ++r) out[r * 128] = (__bf16)S[r];
#pragma unroll
    for (int r = 0; r < 4; ++r) S[r] = df * S[r] + u[r];
  }
}

// ---- stage-3 attention + fused RMS-norm + gate ----
__global__ __launch_bounds__(256) void attn2_kernel(const __bf16* __restrict__ qb,
    const __bf16* __restrict__ kb, const __bf16* __restrict__ vtb,
    const __bf16* __restrict__ St, const __bf16* __restrict__ gateb,
    __bf16* __restrict__ ynormb) {
  __shared__ __bf16 kl[64 * 128];
  __shared__ __bf16 vl[128 * 64];
  __shared__ __bf16 pl[4][16 * 64];
  int h = blockIdx.x >> 5, qt = blockIdx.x & 31;
  int g = h >> 2;
  int w = threadIdx.x >> 6, l = threadIdx.x & 63;
  int lr = l & 15, lg = l >> 4;
  int t0b = qt * 64;
  int t0 = t0b + w * 16;
  bf16x8 qf[4];
#pragma unroll
  for (int kbk = 0; kbk < 4; ++kbk)
    qf[kbk] = *(const bf16x8*)(qb + ((size_t)h * T_SEQ + t0 + lr) * DH + kbk * 32 + lg * 8);
  float gamma = 1.0f - exp2f(-5.0f - (float)h);
  float l2g = log2f(gamma);
  const float scale = 0.088388347648318447f;  // 1/sqrt(128)
  int s0 = t0b;
#pragma unroll
  for (int it = 0; it < 4; ++it) {
    int fg = it * 256 + threadIdx.x;
    {
      int ss = fg >> 4, gr = fg & 15;
      bf16x8 kv = *(const bf16x8*)(kb + ((size_t)g * T_SEQ + s0 + ss) * DH + gr * 8);
      *(bf16x8*)((char*)kl + ss * 256 + ((gr * 16) ^ ((ss & 7) << 4))) = kv;
    }
    {
      int d = fg >> 3, gv = fg & 7;
      bf16x8 vv = *(const bf16x8*)(vtb + ((size_t)g * DH + d) * T_SEQ + s0 + gv * 8);
      *(bf16x8*)((char*)vl + d * 128 + ((gv * 16) ^ ((d & 7) << 4))) = vv;
    }
  }
  float wfac = scale * exp2f(l2g * (float)(w * 16 + lr));
  bf16x8 qwf[4];
#pragma unroll
  for (int kbk = 0; kbk < 4; ++kbk)
#pragma unroll
    for (int e = 0; e < 8; ++e) qwf[kbk][e] = (__bf16)((float)qf[kbk][e] * wfac);
  f32x4 acc[8] = {};
  const __bf16* Sb = St + (size_t)(h * NCHUNK + qt) * 16384;
#pragma unroll
  for (int dc = 0; dc < 8; ++dc)
#pragma unroll
    for (int kc = 0; kc < 4; ++kc) {
      bf16x8 sf = *(const bf16x8*)(Sb + (dc * 16 + lr) * 128 + kc * 32 + lg * 8);
      acc[dc] = __builtin_amdgcn_mfma_f32_16x16x32_bf16(qwf[kc], sf, acc[dc], 0, 0, 0);
    }
  __syncthreads();
#pragma unroll
  for (int sc = 0; sc < 4; ++sc) {
    f32x4 p = {0.f, 0.f, 0.f, 0.f};
    int srow = sc * 16 + lr;
#pragma unroll
    for (int kbk = 0; kbk < 4; ++kbk) {
      bf16x8 kf = *(const bf16x8*)((char*)kl + srow * 256 +
                                   ((kbk * 64 + lg * 16) ^ ((srow & 7) << 4)));
      p = __builtin_amdgcn_mfma_f32_16x16x32_bf16(qf[kbk], kf, p, 0, 0, 0);
    }
#pragma unroll
    for (int r = 0; r < 4; ++r) {
      int tl = lg * 4 + r;
      int diff = (w * 16 + tl) - srow;
      float val = 0.0f;
      if (diff >= 0) val = p[r] * scale * exp2f((float)diff * l2g);
      *(__bf16*)((char*)(pl[w]) + tl * 128 +
                 (((sc * 16 + lr) * 2) ^ ((tl & 7) << 4))) = (__bf16)val;
    }
  }
  bf16x8 pa[2];
#pragma unroll
  for (int kc = 0; kc < 2; ++kc)
    pa[kc] = *(const bf16x8*)((char*)(pl[w]) + lr * 128 +
                              ((kc * 64 + lg * 16) ^ ((lr & 7) << 4)));
#pragma unroll
  for (int dc = 0; dc < 8; ++dc) {
#pragma unroll
    for (int kc = 0; kc < 2; ++kc) {
      int vrow = dc * 16 + lr;
      bf16x8 vf = *(const bf16x8*)((char*)vl + vrow * 128 +
                                   ((kc * 64 + lg * 16) ^ ((vrow & 7) << 4)));
      acc[dc] = __builtin_amdgcn_mfma_f32_16x16x32_bf16(pa[kc], vf, acc[dc], 0, 0, 0);
    }
  }
  float rs[4];
#pragma unroll
  for (int r = 0; r < 4; ++r) {
    float ssum = 0.f;
#pragma unroll
    for (int dc = 0; dc < 8; ++dc) ssum += acc[dc][r] * acc[dc][r];
    ssum += __shfl_xor(ssum, 1, 64);
    ssum += __shfl_xor(ssum, 2, 64);
    ssum += __shfl_xor(ssum, 4, 64);
    ssum += __shfl_xor(ssum, 8, 64);
    rs[r] = rsqrtf(ssum * (1.0f / 128.0f) + 1e-5f);
  }
#pragma unroll
  for (int dc = 0; dc < 8; ++dc)
#pragma unroll
    for (int r = 0; r < 4; ++r) {
      size_t idx = (size_t)(t0 + lg * 4 + r) * CDIM + h * DH + dc * 16 + lr;
      float gv = (float)gateb[idx];
      ynormb[idx] = (__bf16)(acc[dc][r] * rs[r] * gv);
    }
}

// ---------------- GEMM: 64x128 tile, BK=64, gload_lds + XOR swizzle ----------------
// PROFILING: idempotent internal repeat (acc reset each rep) to surface PMC counters.
template<int MODE>
__global__ __launch_bounds__(256) void gemm_gl_kernel(
    const __bf16* __restrict__ A, const __bf16* __restrict__ Bt,
    float* __restrict__ Cf, __bf16* __restrict__ Cg, int M, int N, int K, int rep) {
  __shared__ __bf16 Asb[64 * 64];
  __shared__ __bf16 Bsb[128 * 64];
  int m0 = blockIdx.x * 64, n0 = blockIdx.y * 128;
  int tid = threadIdx.x;
  int w = tid >> 6, l = tid & 63;
  int wr = w >> 1, wc = w & 1;
  int lr = l & 15, lg = l >> 4;
  int nk = K >> 6;
  const __bf16* Ab = A + (size_t)m0 * K;
  const __bf16* Bb = Bt + (size_t)n0 * K;
  f32x4 acc[2][4];
  for (int rp = 0; rp < rep; ++rp) {
    asm volatile("" ::: "memory");
#pragma unroll
    for (int i = 0; i < 2; ++i)
#pragma unroll
      for (int j = 0; j < 4; ++j) acc[i][j] = f32x4{0.f, 0.f, 0.f, 0.f};
    for (int kt = 0; kt < nk; ++kt) {
      int k0 = kt << 6;
#pragma unroll
      for (int c = 0; c < 2; ++c) {
        int ca = c * 256 + tid;
        int row = ca >> 3, kseg = ca & 7;
        gl_lds16(Ab + (size_t)row * K + k0 + ((kseg ^ (row & 7)) << 3), Asb + ca * 8);
      }
#pragma unroll
      for (int c = 0; c < 4; ++c) {
        int cb = c * 256 + tid;
        int row = cb >> 3, kseg = cb & 7;
        gl_lds16(Bb + (size_t)row * K + k0 + ((kseg ^ (row & 7)) << 3), Bsb + cb * 8);
      }
      __syncthreads();
      bf16x8 av[2][2], bv[4][2];
#pragma unroll
      for (int i = 0; i < 2; ++i)
#pragma unroll
        for (int kk = 0; kk < 2; ++kk) {
          int row = wr * 32 + i * 16 + lr;
          av[i][kk] = *(const bf16x8*)((const char*)Asb +
              ((row * 128 + kk * 64 + lg * 16) ^ ((lr & 7) << 4)));
        }
#pragma unroll
      for (int j = 0; j < 4; ++j)
#pragma unroll
        for (int kk = 0; kk < 2; ++kk) {
          int row = wc * 64 + j * 16 + lr;
          bv[j][kk] = *(const bf16x8*)((const char*)Bsb +
              ((row * 128 + kk * 64 + lg * 16) ^ ((lr & 7) << 4)));
        }
#pragma unroll
      for (int kk = 0; kk < 2; ++kk)
#pragma unroll
        for (int i = 0; i < 2; ++i)
#pragma unroll
          for (int j = 0; j < 4; ++j)
            acc[i][j] = __builtin_amdgcn_mfma_f32_16x16x32_bf16(av[i][kk], bv[j][kk],
                                                                acc[i][j], 0, 0, 0);
      __syncthreads();
    }
  }
#pragma unroll
  for (int i = 0; i < 2; ++i) {
    int row = m0 + wr * 32 + i * 16 + lg * 4;
#pragma unroll
    for (int j = 0; j < 4; ++j) {
      int col = n0 + wc * 64 + j * 16 + lr;
#pragma unroll
      for (int r = 0; r < 4; ++r) {
        float z = acc[i][j][r];
        if (MODE == 0) {
          Cf[(size_t)(row + r) * N + col] = z;
        } else {
          if (n0 < 3072) {
            Cf[(size_t)(row + r) * 3072 + col] = z;
          } else {
            float sv = z / (1.0f + expf(-z));
            Cg[(size_t)(row + r) * 2048 + (col - 3072)] = (__bf16)sv;
          }
        }
      }
    }
  }
}

extern "C" void kernel_launch(void* const* d_in, const int* in_sizes, int n_in,
                              void* d_out, int out_size, void* d_ws, size_t ws_size,
                              hipStream_t stream) {
  const float* x    = (const float*)d_in[0];
  const float* cosb = (const float*)d_in[1];
  const float* sinb = (const float*)d_in[2];
  // d_in[3] = mask (268MB) -- computed analytically, never read
  const float* Wr   = (const float*)d_in[4];
  const float* Wg   = (const float*)d_in[5];
  const float* Wp   = (const float*)d_in[6];

  char* ws = (char*)d_ws;
  size_t off = 0;
  auto alloc = [&](size_t bytes) { void* p = ws + off; off += (bytes + 255) & ~(size_t)255; return p; };
  __bf16* xb     = (__bf16*)alloc((size_t)CDIM * CDIM * 2);          // 8MB
  __bf16* wtb    = (__bf16*)alloc((size_t)5120 * CDIM * 2);          // 20MB (W_reten^T|W_gate^T)
  __bf16* wpb    = (__bf16*)alloc((size_t)CDIM * CDIM * 2);          // 8MB
  char*   qkvblk = (char*)  alloc((size_t)T_SEQ * 3072 * 4);         // 24MB (qkv f32; later ynorm)
  __bf16* qb     = (__bf16*)alloc((size_t)NH * T_SEQ * DH * 2);      // 8MB
  __bf16* kbp    = (__bf16*)alloc((size_t)NG * T_SEQ * DH * 2);      // 2MB
  __bf16* vtb    = (__bf16*)alloc((size_t)NG * DH * T_SEQ * 2);      // 2MB
  __bf16* ktb    = (__bf16*)alloc((size_t)NG * DH * T_SEQ * 2);      // 2MB
  __bf16* gateb  = (__bf16*)alloc((size_t)CDIM * CDIM * 2);          // 8MB
  __bf16* Stb    = (__bf16*)alloc((size_t)NH * NCHUNK * 128 * 128 * 2); // 16MB
  float*  qkv    = (float*)qkvblk;
  __bf16* ynormb = (__bf16*)qkvblk;    // alias: qkv fully consumed before attn2 writes

  // PROFILING ROUND: GEMMs repeated to surface above the ~160us harness fills.
  const int REP_G1 = 16, REP_G3 = 32;

  pre_kernel<<<5632, 256, 0, stream>>>(x, Wr, Wg, Wp, xb, wtb, wpb);
  gemm_gl_kernel<1><<<dim3(32, 40), 256, 0, stream>>>(xb, wtb, qkv, gateb, 2048, 5120, 2048,
                                                      REP_G1);
  ropekt_kernel<<<2048 + NG * 32 * 2, 256, 0, stream>>>(qkv, cosb, sinb, qb, kbp, vtb, ktb);
  uscan_kernel<<<256, 256, 0, stream>>>(vtb, ktb, Stb);
  attn2_kernel<<<NH * NCHUNK, 256, 0, stream>>>(qb, kbp, vtb, Stb, gateb, ynormb);
  gemm_gl_kernel<0><<<dim3(32, 16), 256, 0, stream>>>(ynormb, wpb, (float*)d_out, nullptr,
                                                      2048, 2048, 2048, REP_G3);
}

// Round 9
// 163.982 us; speedup vs baseline: 10.6839x; 10.6839x over previous
//
#include <hip/hip_runtime.h>
#include <hip/hip_bf16.h>
#include <cstdint>
#include <cstddef>

typedef __bf16 bf16x8 __attribute__((ext_vector_type(8)));
typedef __bf16 bf16x4 __attribute__((ext_vector_type(4)));
typedef __bf16 bf16x2 __attribute__((ext_vector_type(2)));
typedef float  f32x4  __attribute__((ext_vector_type(4)));
typedef float  f32x2  __attribute__((ext_vector_type(2)));

#define T_SEQ 2048
#define CDIM  2048
#define NH    16
#define NG    4
#define DH    128
#define NCHUNK 32   // T / 64

__device__ __forceinline__ void gl_lds16(const __bf16* g, __bf16* l) {
  __builtin_amdgcn_global_load_lds(
      (const __attribute__((address_space(1))) void*)g,
      (__attribute__((address_space(3))) void*)l, 16, 0, 0);
}

// ---------------- fused preprocess: cast x->bf16, transpose+cast 3 weights ----------------
__global__ __launch_bounds__(256) void pre_kernel(
    const float* __restrict__ x, const float* __restrict__ Wr,
    const float* __restrict__ Wg, const float* __restrict__ Wp,
    __bf16* __restrict__ xb, __bf16* __restrict__ wtb, __bf16* __restrict__ wpb) {
  __shared__ __bf16 tile[64][68];
  int bid = blockIdx.x;
  int tid = threadIdx.x;
  if (bid < 2048) {   // cast x (4M elements)
    size_t i = ((size_t)bid * 256 + tid) * 8;
    f32x4 a = *(const f32x4*)(x + i);
    f32x4 b = *(const f32x4*)(x + i + 4);
    bf16x8 o;
#pragma unroll
    for (int j = 0; j < 4; ++j) { o[j] = (__bf16)a[j]; o[4 + j] = (__bf16)b[j]; }
    *(bf16x8*)(xb + i) = o;
    return;
  }
  int rel = bid - 2048;
  const float* W; __bf16* Wt; int N;
  if (rel < 1536)      { W = Wr; Wt = wtb;                        N = 3072; }
  else if (rel < 2560) { W = Wg; Wt = wtb + (size_t)3072 * CDIM;  N = 2048; rel -= 1536; }
  else                 { W = Wp; Wt = wpb;                        N = 2048; rel -= 2560; }
  const int K = 2048;
  int k0 = (rel & 31) * 64, n0 = (rel >> 5) * 64;
  int c4 = (tid & 15) * 4, r = tid >> 4;
#pragma unroll
  for (int rr = 0; rr < 4; ++rr) {
    int row = r + rr * 16;
    f32x4 v = *(const f32x4*)(W + (size_t)(k0 + row) * N + n0 + c4);
#pragma unroll
    for (int j = 0; j < 4; ++j) tile[row][c4 + j] = (__bf16)v[j];
  }
  __syncthreads();
  int n = tid >> 2, seg = tid & 3;
  __bf16 vals[16];
#pragma unroll
  for (int j = 0; j < 16; ++j) vals[j] = tile[seg * 16 + j][n];
  __bf16* dst = Wt + (size_t)(n0 + n) * K + k0 + seg * 16;
  *(bf16x8*)(dst)     = *(bf16x8*)(&vals[0]);
  *(bf16x8*)(dst + 8) = *(bf16x8*)(&vals[8]);
}

// ---------------- fused U+scan: per (h, d2-slice, d1-half) block, sequential over chunks ----
__global__ __launch_bounds__(256) void uscan_kernel(const __bf16* __restrict__ vtb,
                                                    const __bf16* __restrict__ ktb,
                                                    __bf16* __restrict__ St) {
  int bid = blockIdx.x;                 // NH*8*2 = 256
  int h = bid >> 4, m = (bid >> 1) & 7, half = bid & 1;
  int g = h >> 2;
  int tid = threadIdx.x, w = tid >> 6, l = tid & 63, lr = l & 15, lg = l >> 4;
  int jf = half * 4 + w;                // d1 block 0..7
  float l2g = log2f(1.0f - exp2f(-5.0f - (float)h));
  float ginv = exp2f(-l2g);             // 1/gamma
  float df   = exp2f(l2g * 64.0f);      // gamma^64
  float wk[2];
#pragma unroll
  for (int kk = 0; kk < 2; ++kk) wk[kk] = exp2f(l2g * (float)(64 - (kk * 32 + lg * 8)));
  const __bf16* vrow = vtb + ((size_t)g * DH + m * 16 + lr) * T_SEQ;
  const __bf16* krow = ktb + ((size_t)g * DH + jf * 16 + lr) * T_SEQ;
  f32x4 S = {0.f, 0.f, 0.f, 0.f};
  for (int c = 0; c < NCHUNK; ++c) {
    f32x4 u = {0.f, 0.f, 0.f, 0.f};
#pragma unroll
    for (int kk = 0; kk < 2; ++kk) {
      int j0 = c * 64 + kk * 32 + lg * 8;
      bf16x8 av = *(const bf16x8*)(vrow + j0);
      bf16x8 bv = *(const bf16x8*)(krow + j0);
      bf16x8 aw;
      float wj = wk[kk];
#pragma unroll
      for (int jj = 0; jj < 8; ++jj) { aw[jj] = (__bf16)((float)av[jj] * wj); wj *= ginv; }
      u = __builtin_amdgcn_mfma_f32_16x16x32_bf16(aw, bv, u, 0, 0, 0);
    }
    __bf16* out = St + ((size_t)(h * NCHUNK + c) * 128 + m * 16 + lg * 4) * 128 + jf * 16 + lr;
#pragma unroll
    for (int r = 0; r < 4; ++r) out[r * 128] = (__bf16)S[r];
#pragma unroll
    for (int r = 0; r < 4; ++r) S[r] = df * S[r] + u[r];
  }
}

// ---- stage-3 attention + fused RMS-norm + gate ----
__global__ __launch_bounds__(256) void attn2_kernel(const __bf16* __restrict__ qb,
    const __bf16* __restrict__ kb, const __bf16* __restrict__ vtb,
    const __bf16* __restrict__ St, const __bf16* __restrict__ gateb,
    __bf16* __restrict__ ynormb) {
  __shared__ __bf16 kl[64 * 128];
  __shared__ __bf16 vl[128 * 64];
  __shared__ __bf16 pl[4][16 * 64];
  int h = blockIdx.x >> 5, qt = blockIdx.x & 31;
  int g = h >> 2;
  int w = threadIdx.x >> 6, l = threadIdx.x & 63;
  int lr = l & 15, lg = l >> 4;
  int t0b = qt * 64;
  int t0 = t0b + w * 16;
  bf16x8 qf[4];
#pragma unroll
  for (int kbk = 0; kbk < 4; ++kbk)
    qf[kbk] = *(const bf16x8*)(qb + ((size_t)h * T_SEQ + t0 + lr) * DH + kbk * 32 + lg * 8);
  float gamma = 1.0f - exp2f(-5.0f - (float)h);
  float l2g = log2f(gamma);
  const float scale = 0.088388347648318447f;  // 1/sqrt(128)
  int s0 = t0b;
#pragma unroll
  for (int it = 0; it < 4; ++it) {
    int fg = it * 256 + threadIdx.x;
    {
      int ss = fg >> 4, gr = fg & 15;
      bf16x8 kv = *(const bf16x8*)(kb + ((size_t)g * T_SEQ + s0 + ss) * DH + gr * 8);
      *(bf16x8*)((char*)kl + ss * 256 + ((gr * 16) ^ ((ss & 7) << 4))) = kv;
    }
    {
      int d = fg >> 3, gv = fg & 7;
      bf16x8 vv = *(const bf16x8*)(vtb + ((size_t)g * DH + d) * T_SEQ + s0 + gv * 8);
      *(bf16x8*)((char*)vl + d * 128 + ((gv * 16) ^ ((d & 7) << 4))) = vv;
    }
  }
  float wfac = scale * exp2f(l2g * (float)(w * 16 + lr));
  bf16x8 qwf[4];
#pragma unroll
  for (int kbk = 0; kbk < 4; ++kbk)
#pragma unroll
    for (int e = 0; e < 8; ++e) qwf[kbk][e] = (__bf16)((float)qf[kbk][e] * wfac);
  f32x4 acc[8] = {};
  const __bf16* Sb = St + (size_t)(h * NCHUNK + qt) * 16384;
#pragma unroll
  for (int dc = 0; dc < 8; ++dc)
#pragma unroll
    for (int kc = 0; kc < 4; ++kc) {
      bf16x8 sf = *(const bf16x8*)(Sb + (dc * 16 + lr) * 128 + kc * 32 + lg * 8);
      acc[dc] = __builtin_amdgcn_mfma_f32_16x16x32_bf16(qwf[kc], sf, acc[dc], 0, 0, 0);
    }
  __syncthreads();
#pragma unroll
  for (int sc = 0; sc < 4; ++sc) {
    f32x4 p = {0.f, 0.f, 0.f, 0.f};
    int srow = sc * 16 + lr;
#pragma unroll
    for (int kbk = 0; kbk < 4; ++kbk) {
      bf16x8 kf = *(const bf16x8*)((char*)kl + srow * 256 +
                                   ((kbk * 64 + lg * 16) ^ ((srow & 7) << 4)));
      p = __builtin_amdgcn_mfma_f32_16x16x32_bf16(qf[kbk], kf, p, 0, 0, 0);
    }
#pragma unroll
    for (int r = 0; r < 4; ++r) {
      int tl = lg * 4 + r;
      int diff = (w * 16 + tl) - srow;
      float val = 0.0f;
      if (diff >= 0) val = p[r] * scale * exp2f((float)diff * l2g);
      *(__bf16*)((char*)(pl[w]) + tl * 128 +
                 (((sc * 16 + lr) * 2) ^ ((tl & 7) << 4))) = (__bf16)val;
    }
  }
  bf16x8 pa[2];
#pragma unroll
  for (int kc = 0; kc < 2; ++kc)
    pa[kc] = *(const bf16x8*)((char*)(pl[w]) + lr * 128 +
                              ((kc * 64 + lg * 16) ^ ((lr & 7) << 4)));
#pragma unroll
  for (int dc = 0; dc < 8; ++dc) {
#pragma unroll
    for (int kc = 0; kc < 2; ++kc) {
      int vrow = dc * 16 + lr;
      bf16x8 vf = *(const bf16x8*)((char*)vl + vrow * 128 +
                                   ((kc * 64 + lg * 16) ^ ((vrow & 7) << 4)));
      acc[dc] = __builtin_amdgcn_mfma_f32_16x16x32_bf16(pa[kc], vf, acc[dc], 0, 0, 0);
    }
  }
  float rs[4];
#pragma unroll
  for (int r = 0; r < 4; ++r) {
    float ssum = 0.f;
#pragma unroll
    for (int dc = 0; dc < 8; ++dc) ssum += acc[dc][r] * acc[dc][r];
    ssum += __shfl_xor(ssum, 1, 64);
    ssum += __shfl_xor(ssum, 2, 64);
    ssum += __shfl_xor(ssum, 4, 64);
    ssum += __shfl_xor(ssum, 8, 64);
    rs[r] = rsqrtf(ssum * (1.0f / 128.0f) + 1e-5f);
  }
#pragma unroll
  for (int dc = 0; dc < 8; ++dc)
#pragma unroll
    for (int r = 0; r < 4; ++r) {
      size_t idx = (size_t)(t0 + lg * 4 + r) * CDIM + h * DH + dc * 16 + lr;
      float gv = (float)gateb[idx];
      ynormb[idx] = (__bf16)(acc[dc][r] * rs[r] * gv);
    }
}

// ---------------- GEMM: 64x128 tile, BK=64, gload_lds + XOR swizzle ----------------
// MODE 0: Cf[row*N+col] = z (f32).
// MODE 1: fused epilogue -- n0<3072: RoPE q,k in-register (shfl pair exchange) and
//   scatter to qb[h][t][d], kb[g][t][d], ktb[g][d][t]; v -> vtb[g][d][t]; all bf16.
//   n0>=3072: silu(z) -> gateb. Value-identical to the old qkv->ropekt path.
template<int MODE>
__global__ __launch_bounds__(256) void gemm_gl_kernel(
    const __bf16* __restrict__ A, const __bf16* __restrict__ Bt,
    float* __restrict__ Cf, __bf16* __restrict__ Cg,
    const float* __restrict__ cosb, const float* __restrict__ sinb,
    __bf16* __restrict__ qb, __bf16* __restrict__ kb,
    __bf16* __restrict__ vtb, __bf16* __restrict__ ktb,
    int M, int N, int K) {
  __shared__ __bf16 Asb[64 * 64];
  __shared__ __bf16 Bsb[128 * 64];
  int m0 = blockIdx.x * 64, n0 = blockIdx.y * 128;
  int tid = threadIdx.x;
  int w = tid >> 6, l = tid & 63;
  int wr = w >> 1, wc = w & 1;
  int lr = l & 15, lg = l >> 4;
  int nk = K >> 6;
  const __bf16* Ab = A + (size_t)m0 * K;
  const __bf16* Bb = Bt + (size_t)n0 * K;
  f32x4 acc[2][4] = {};
  for (int kt = 0; kt < nk; ++kt) {
    int k0 = kt << 6;
#pragma unroll
    for (int c = 0; c < 2; ++c) {
      int ca = c * 256 + tid;
      int row = ca >> 3, kseg = ca & 7;
      gl_lds16(Ab + (size_t)row * K + k0 + ((kseg ^ (row & 7)) << 3), Asb + ca * 8);
    }
#pragma unroll
    for (int c = 0; c < 4; ++c) {
      int cb = c * 256 + tid;
      int row = cb >> 3, kseg = cb & 7;
      gl_lds16(Bb + (size_t)row * K + k0 + ((kseg ^ (row & 7)) << 3), Bsb + cb * 8);
    }
    __syncthreads();
    bf16x8 av[2][2], bv[4][2];
#pragma unroll
    for (int i = 0; i < 2; ++i)
#pragma unroll
      for (int kk = 0; kk < 2; ++kk) {
        int row = wr * 32 + i * 16 + lr;
        av[i][kk] = *(const bf16x8*)((const char*)Asb +
            ((row * 128 + kk * 64 + lg * 16) ^ ((lr & 7) << 4)));
      }
#pragma unroll
    for (int j = 0; j < 4; ++j)
#pragma unroll
      for (int kk = 0; kk < 2; ++kk) {
        int row = wc * 64 + j * 16 + lr;
        bv[j][kk] = *(const bf16x8*)((const char*)Bsb +
            ((row * 128 + kk * 64 + lg * 16) ^ ((lr & 7) << 4)));
      }
#pragma unroll
    for (int kk = 0; kk < 2; ++kk)
#pragma unroll
      for (int i = 0; i < 2; ++i)
#pragma unroll
        for (int j = 0; j < 4; ++j)
          acc[i][j] = __builtin_amdgcn_mfma_f32_16x16x32_bf16(av[i][kk], bv[j][kk],
                                                              acc[i][j], 0, 0, 0);
    __syncthreads();
  }
  if (MODE == 0) {
#pragma unroll
    for (int i = 0; i < 2; ++i) {
      int row = m0 + wr * 32 + i * 16 + lg * 4;
#pragma unroll
      for (int j = 0; j < 4; ++j) {
        int col = n0 + wc * 64 + j * 16 + lr;
#pragma unroll
        for (int r = 0; r < 4; ++r)
          Cf[(size_t)(row + r) * N + col] = acc[i][j][r];
      }
    }
    return;
  }
  // MODE 1 fused epilogue
  if (n0 >= 3072) {
#pragma unroll
    for (int i = 0; i < 2; ++i) {
      int row = m0 + wr * 32 + i * 16 + lg * 4;
#pragma unroll
      for (int j = 0; j < 4; ++j) {
        int col = n0 + wc * 64 + j * 16 + lr;
#pragma unroll
        for (int r = 0; r < 4; ++r) {
          float z = acc[i][j][r];
          float sv = z / (1.0f + expf(-z));
          Cg[(size_t)(row + r) * 2048 + (col - 3072)] = (__bf16)sv;
        }
      }
    }
    return;
  }
  // qkv section: rope q,k in-register and scatter; v -> vtb
#pragma unroll
  for (int i = 0; i < 2; ++i) {
    int row0 = m0 + wr * 32 + i * 16 + lg * 4;
#pragma unroll
    for (int j = 0; j < 4; ++j) {
      int cb = n0 + wc * 64 + j * 16;            // frag base col (wave-uniform)
      int g = cb / 768, cm = cb % 768;
      int dbase = (cm < 512) ? (cm & 127) : (cm < 640) ? (cm - 512) : (cm - 640);
      int d = dbase + lr;
      float ov[4];
      if (cm < 640) {                            // rope (q or k)
#pragma unroll
        for (int r = 0; r < 4; ++r) {
          float z = acc[i][j][r];
          float pz = __shfl_xor(z, 1, 64);       // pair partner (col parity == lr parity)
          int t = row0 + r;
          float cc = cosb[t * 64 + (d >> 1)];
          float ss = sinb[t * 64 + (d >> 1)];
          ov[r] = (lr & 1) ? (pz * ss + z * cc) : (z * cc - pz * ss);
        }
      } else {
#pragma unroll
        for (int r = 0; r < 4; ++r) ov[r] = acc[i][j][r];
      }
      if (cm < 512) {                            // q -> qb[h][t][d]
        int hh = g * 4 + (cm >> 7);
#pragma unroll
        for (int r = 0; r < 4; ++r)
          qb[((size_t)hh * T_SEQ + row0 + r) * DH + d] = (__bf16)ov[r];
      } else if (cm < 640) {                     // k -> kb[g][t][d] and ktb[g][d][t]
        bf16x4 kv;
#pragma unroll
        for (int r = 0; r < 4; ++r) {
          kv[r] = (__bf16)ov[r];
          kb[((size_t)g * T_SEQ + row0 + r) * DH + d] = kv[r];
        }
        *(bf16x4*)(ktb + ((size_t)g * DH + d) * T_SEQ + row0) = kv;
      } else {                                   // v -> vtb[g][d][t]
        bf16x4 vv;
#pragma unroll
        for (int r = 0; r < 4; ++r) vv[r] = (__bf16)ov[r];
        *(bf16x4*)(vtb + ((size_t)g * DH + d) * T_SEQ + row0) = vv;
      }
    }
  }
}

extern "C" void kernel_launch(void* const* d_in, const int* in_sizes, int n_in,
                              void* d_out, int out_size, void* d_ws, size_t ws_size,
                              hipStream_t stream) {
  const float* x    = (const float*)d_in[0];
  const float* cosb = (const float*)d_in[1];
  const float* sinb = (const float*)d_in[2];
  // d_in[3] = mask (268MB) -- computed analytically, never read
  const float* Wr   = (const float*)d_in[4];
  const float* Wg   = (const float*)d_in[5];
  const float* Wp   = (const float*)d_in[6];

  char* ws = (char*)d_ws;
  size_t off = 0;
  auto alloc = [&](size_t bytes) { void* p = ws + off; off += (bytes + 255) & ~(size_t)255; return p; };
  __bf16* xb     = (__bf16*)alloc((size_t)CDIM * CDIM * 2);          // 8MB
  __bf16* wtb    = (__bf16*)alloc((size_t)5120 * CDIM * 2);          // 20MB (W_reten^T|W_gate^T)
  __bf16* wpb    = (__bf16*)alloc((size_t)CDIM * CDIM * 2);          // 8MB
  __bf16* qb     = (__bf16*)alloc((size_t)NH * T_SEQ * DH * 2);      // 8MB
  __bf16* kbp    = (__bf16*)alloc((size_t)NG * T_SEQ * DH * 2);      // 2MB
  __bf16* vtb    = (__bf16*)alloc((size_t)NG * DH * T_SEQ * 2);      // 2MB
  __bf16* ktb    = (__bf16*)alloc((size_t)NG * DH * T_SEQ * 2);      // 2MB
  __bf16* gateb  = (__bf16*)alloc((size_t)CDIM * CDIM * 2);          // 8MB
  __bf16* Stb    = (__bf16*)alloc((size_t)NH * NCHUNK * 128 * 128 * 2); // 16MB
  __bf16* ynormb = (__bf16*)alloc((size_t)T_SEQ * CDIM * 2);         // 8MB

  // 1) preprocess: cast x + transpose/cast all weights
  pre_kernel<<<5632, 256, 0, stream>>>(x, Wr, Wg, Wp, xb, wtb, wpb);
  // 2) fused: x @ [W_reten | W_gate] with in-epilogue RoPE/scatter/transpose + silu gate
  gemm_gl_kernel<1><<<dim3(32, 40), 256, 0, stream>>>(
      xb, wtb, nullptr, gateb, cosb, sinb, qb, kbp, vtb, ktb, 2048, 5120, 2048);
  // 3) fused per-chunk decayed KV outer products + state scan -> St bf16
  uscan_kernel<<<256, 256, 0, stream>>>(vtb, ktb, Stb);
  // 4) attention (intra tile + q@S_c) + fused RMS-norm + gate -> ynorm bf16 [T][C]
  attn2_kernel<<<NH * NCHUNK, 256, 0, stream>>>(qb, kbp, vtb, Stb, gateb, ynormb);
  // 5) out = (g*y_norm) @ W_proj
  gemm_gl_kernel<0><<<dim3(32, 16), 256, 0, stream>>>(
      ynormb, wpb, (float*)d_out, nullptr, nullptr, nullptr, nullptr, nullptr, nullptr, nullptr,
      2048, 2048, 2048);
}

// Round 10
// 155.000 us; speedup vs baseline: 11.3031x; 1.0580x over previous
//
#include <hip/hip_runtime.h>
#include <hip/hip_bf16.h>
#include <cstdint>
#include <cstddef>

typedef __bf16 bf16x8 __attribute__((ext_vector_type(8)));
typedef __bf16 bf16x4 __attribute__((ext_vector_type(4)));
typedef __bf16 bf16x2 __attribute__((ext_vector_type(2)));
typedef float  f32x4  __attribute__((ext_vector_type(4)));
typedef float  f32x2  __attribute__((ext_vector_type(2)));

#define T_SEQ 2048
#define CDIM  2048
#define NH    16
#define NG    4
#define DH    128
#define NCHUNK 32   // T / 64

__device__ __forceinline__ void gl_lds16(const __bf16* g, __bf16* l) {
  __builtin_amdgcn_global_load_lds(
      (const __attribute__((address_space(1))) void*)g,
      (__attribute__((address_space(3))) void*)l, 16, 0, 0);
}

// ---------------- fused preprocess: cast x->bf16, transpose+cast 3 weights ----------------
__global__ __launch_bounds__(256) void pre_kernel(
    const float* __restrict__ x, const float* __restrict__ Wr,
    const float* __restrict__ Wg, const float* __restrict__ Wp,
    __bf16* __restrict__ xb, __bf16* __restrict__ wtb, __bf16* __restrict__ wpb) {
  __shared__ __bf16 tile[64][68];
  int bid = blockIdx.x;
  int tid = threadIdx.x;
  if (bid < 2048) {   // cast x (4M elements)
    size_t i = ((size_t)bid * 256 + tid) * 8;
    f32x4 a = *(const f32x4*)(x + i);
    f32x4 b = *(const f32x4*)(x + i + 4);
    bf16x8 o;
#pragma unroll
    for (int j = 0; j < 4; ++j) { o[j] = (__bf16)a[j]; o[4 + j] = (__bf16)b[j]; }
    *(bf16x8*)(xb + i) = o;
    return;
  }
  int rel = bid - 2048;
  const float* W; __bf16* Wt; int N;
  if (rel < 1536)      { W = Wr; Wt = wtb;                        N = 3072; }
  else if (rel < 2560) { W = Wg; Wt = wtb + (size_t)3072 * CDIM;  N = 2048; rel -= 1536; }
  else                 { W = Wp; Wt = wpb;                        N = 2048; rel -= 2560; }
  const int K = 2048;
  int k0 = (rel & 31) * 64, n0 = (rel >> 5) * 64;
  int c4 = (tid & 15) * 4, r = tid >> 4;
#pragma unroll
  for (int rr = 0; rr < 4; ++rr) {
    int row = r + rr * 16;
    f32x4 v = *(const f32x4*)(W + (size_t)(k0 + row) * N + n0 + c4);
#pragma unroll
    for (int j = 0; j < 4; ++j) tile[row][c4 + j] = (__bf16)v[j];
  }
  __syncthreads();
  int n = tid >> 2, seg = tid & 3;
  __bf16 vals[16];
#pragma unroll
  for (int j = 0; j < 16; ++j) vals[j] = tile[seg * 16 + j][n];
  __bf16* dst = Wt + (size_t)(n0 + n) * K + k0 + seg * 16;
  *(bf16x8*)(dst)     = *(bf16x8*)(&vals[0]);
  *(bf16x8*)(dst + 8) = *(bf16x8*)(&vals[8]);
}

// ---------------- fused U+scan: per (h, d2-slice, d1-half) block, sequential over chunks ----
__global__ __launch_bounds__(256) void uscan_kernel(const __bf16* __restrict__ vtb,
                                                    const __bf16* __restrict__ ktb,
                                                    __bf16* __restrict__ St) {
  int bid = blockIdx.x;                 // NH*8*2 = 256
  int h = bid >> 4, m = (bid >> 1) & 7, half = bid & 1;
  int g = h >> 2;
  int tid = threadIdx.x, w = tid >> 6, l = tid & 63, lr = l & 15, lg = l >> 4;
  int jf = half * 4 + w;                // d1 block 0..7
  float l2g = log2f(1.0f - exp2f(-5.0f - (float)h));
  float ginv = exp2f(-l2g);             // 1/gamma
  float df   = exp2f(l2g * 64.0f);      // gamma^64
  float wk[2];
#pragma unroll
  for (int kk = 0; kk < 2; ++kk) wk[kk] = exp2f(l2g * (float)(64 - (kk * 32 + lg * 8)));
  const __bf16* vrow = vtb + ((size_t)g * DH + m * 16 + lr) * T_SEQ;
  const __bf16* krow = ktb + ((size_t)g * DH + jf * 16 + lr) * T_SEQ;
  f32x4 S = {0.f, 0.f, 0.f, 0.f};
  for (int c = 0; c < NCHUNK; ++c) {
    f32x4 u = {0.f, 0.f, 0.f, 0.f};
#pragma unroll
    for (int kk = 0; kk < 2; ++kk) {
      int j0 = c * 64 + kk * 32 + lg * 8;
      bf16x8 av = *(const bf16x8*)(vrow + j0);
      bf16x8 bv = *(const bf16x8*)(krow + j0);
      bf16x8 aw;
      float wj = wk[kk];
#pragma unroll
      for (int jj = 0; jj < 8; ++jj) { aw[jj] = (__bf16)((float)av[jj] * wj); wj *= ginv; }
      u = __builtin_amdgcn_mfma_f32_16x16x32_bf16(aw, bv, u, 0, 0, 0);
    }
    __bf16* out = St + ((size_t)(h * NCHUNK + c) * 128 + m * 16 + lg * 4) * 128 + jf * 16 + lr;
#pragma unroll
    for (int r = 0; r < 4; ++r) out[r * 128] = (__bf16)S[r];
#pragma unroll
    for (int r = 0; r < 4; ++r) S[r] = df * S[r] + u[r];
  }
}

// ---- stage-3 attention + fused RMS-norm + gate ----
__global__ __launch_bounds__(256) void attn2_kernel(const __bf16* __restrict__ qb,
    const __bf16* __restrict__ kb, const __bf16* __restrict__ vtb,
    const __bf16* __restrict__ St, const __bf16* __restrict__ gateb,
    __bf16* __restrict__ ynormb) {
  __shared__ __bf16 kl[64 * 128];
  __shared__ __bf16 vl[128 * 64];
  __shared__ __bf16 pl[4][16 * 64];
  int h = blockIdx.x >> 5, qt = blockIdx.x & 31;
  int g = h >> 2;
  int w = threadIdx.x >> 6, l = threadIdx.x & 63;
  int lr = l & 15, lg = l >> 4;
  int t0b = qt * 64;
  int t0 = t0b + w * 16;
  bf16x8 qf[4];
#pragma unroll
  for (int kbk = 0; kbk < 4; ++kbk)
    qf[kbk] = *(const bf16x8*)(qb + ((size_t)h * T_SEQ + t0 + lr) * DH + kbk * 32 + lg * 8);
  float gamma = 1.0f - exp2f(-5.0f - (float)h);
  float l2g = log2f(gamma);
  const float scale = 0.088388347648318447f;  // 1/sqrt(128)
  int s0 = t0b;
#pragma unroll
  for (int it = 0; it < 4; ++it) {
    int fg = it * 256 + threadIdx.x;
    {
      int ss = fg >> 4, gr = fg & 15;
      bf16x8 kv = *(const bf16x8*)(kb + ((size_t)g * T_SEQ + s0 + ss) * DH + gr * 8);
      *(bf16x8*)((char*)kl + ss * 256 + ((gr * 16) ^ ((ss & 7) << 4))) = kv;
    }
    {
      int d = fg >> 3, gv = fg & 7;
      bf16x8 vv = *(const bf16x8*)(vtb + ((size_t)g * DH + d) * T_SEQ + s0 + gv * 8);
      *(bf16x8*)((char*)vl + d * 128 + ((gv * 16) ^ ((d & 7) << 4))) = vv;
    }
  }
  float wfac = scale * exp2f(l2g * (float)(w * 16 + lr));
  bf16x8 qwf[4];
#pragma unroll
  for (int kbk = 0; kbk < 4; ++kbk)
#pragma unroll
    for (int e = 0; e < 8; ++e) qwf[kbk][e] = (__bf16)((float)qf[kbk][e] * wfac);
  f32x4 acc[8] = {};
  const __bf16* Sb = St + (size_t)(h * NCHUNK + qt) * 16384;
#pragma unroll
  for (int dc = 0; dc < 8; ++dc)
#pragma unroll
    for (int kc = 0; kc < 4; ++kc) {
      bf16x8 sf = *(const bf16x8*)(Sb + (dc * 16 + lr) * 128 + kc * 32 + lg * 8);
      acc[dc] = __builtin_amdgcn_mfma_f32_16x16x32_bf16(qwf[kc], sf, acc[dc], 0, 0, 0);
    }
  __syncthreads();
#pragma unroll
  for (int sc = 0; sc < 4; ++sc) {
    f32x4 p = {0.f, 0.f, 0.f, 0.f};
    int srow = sc * 16 + lr;
#pragma unroll
    for (int kbk = 0; kbk < 4; ++kbk) {
      bf16x8 kf = *(const bf16x8*)((char*)kl + srow * 256 +
                                   ((kbk * 64 + lg * 16) ^ ((srow & 7) << 4)));
      p = __builtin_amdgcn_mfma_f32_16x16x32_bf16(qf[kbk], kf, p, 0, 0, 0);
    }
#pragma unroll
    for (int r = 0; r < 4; ++r) {
      int tl = lg * 4 + r;
      int diff = (w * 16 + tl) - srow;
      float val = 0.0f;
      if (diff >= 0) val = p[r] * scale * exp2f((float)diff * l2g);
      *(__bf16*)((char*)(pl[w]) + tl * 128 +
                 (((sc * 16 + lr) * 2) ^ ((tl & 7) << 4))) = (__bf16)val;
    }
  }
  bf16x8 pa[2];
#pragma unroll
  for (int kc = 0; kc < 2; ++kc)
    pa[kc] = *(const bf16x8*)((char*)(pl[w]) + lr * 128 +
                              ((kc * 64 + lg * 16) ^ ((lr & 7) << 4)));
#pragma unroll
  for (int dc = 0; dc < 8; ++dc) {
#pragma unroll
    for (int kc = 0; kc < 2; ++kc) {
      int vrow = dc * 16 + lr;
      bf16x8 vf = *(const bf16x8*)((char*)vl + vrow * 128 +
                                   ((kc * 64 + lg * 16) ^ ((vrow & 7) << 4)));
      acc[dc] = __builtin_amdgcn_mfma_f32_16x16x32_bf16(pa[kc], vf, acc[dc], 0, 0, 0);
    }
  }
  float rs[4];
#pragma unroll
  for (int r = 0; r < 4; ++r) {
    float ssum = 0.f;
#pragma unroll
    for (int dc = 0; dc < 8; ++dc) ssum += acc[dc][r] * acc[dc][r];
    ssum += __shfl_xor(ssum, 1, 64);
    ssum += __shfl_xor(ssum, 2, 64);
    ssum += __shfl_xor(ssum, 4, 64);
    ssum += __shfl_xor(ssum, 8, 64);
    rs[r] = rsqrtf(ssum * (1.0f / 128.0f) + 1e-5f);
  }
#pragma unroll
  for (int dc = 0; dc < 8; ++dc)
#pragma unroll
    for (int r = 0; r < 4; ++r) {
      size_t idx = (size_t)(t0 + lg * 4 + r) * CDIM + h * DH + dc * 16 + lr;
      float gv = (float)gateb[idx];
      ynormb[idx] = (__bf16)(acc[dc][r] * rs[r] * gv);
    }
}

// ---------------- GEMM: 64x128 tile, BK=64, depth-2 counted-vmcnt LDS double-buffer ----
// Schedule per K-step: compute(cur) -> s_barrier -> stage(cur, kt+2) -> vmcnt(6) -> s_barrier.
// Loads for tile kt+2 stay in flight across compute(kt+1); main loop never drains vmcnt to 0.
// MODE 0: Cf[row*N+col] = z (f32).
// MODE 1: fused epilogue -- n0<3072: RoPE q,k in-register and scatter to qb/kb/ktb, v->vtb;
//   n0>=3072: silu(z) -> gateb.
template<int MODE>
__global__ __launch_bounds__(256) void gemm_gl_kernel(
    const __bf16* __restrict__ A, const __bf16* __restrict__ Bt,
    float* __restrict__ Cf, __bf16* __restrict__ Cg,
    const float* __restrict__ cosb, const float* __restrict__ sinb,
    __bf16* __restrict__ qb, __bf16* __restrict__ kb,
    __bf16* __restrict__ vtb, __bf16* __restrict__ ktb,
    int M, int N, int K) {
  __shared__ __bf16 Asb[2 * 64 * 64];    // 16KB (two 8KB buffers)
  __shared__ __bf16 Bsb[2 * 128 * 64];   // 32KB (two 16KB buffers)
  int m0 = blockIdx.x * 64, n0 = blockIdx.y * 128;
  int tid = threadIdx.x;
  int w = tid >> 6, l = tid & 63;
  int wr = w >> 1, wc = w & 1;
  int lr = l & 15, lg = l >> 4;
  int nk = K >> 6;
  const __bf16* Ab = A + (size_t)m0 * K;
  const __bf16* Bb = Bt + (size_t)n0 * K;
  f32x4 acc[2][4] = {};

  auto stage = [&](int buf, int k0) {
#pragma unroll
    for (int c = 0; c < 2; ++c) {
      int ca = c * 256 + tid, row = ca >> 3, ks = ca & 7;
      gl_lds16(Ab + (size_t)row * K + k0 + ((ks ^ (row & 7)) << 3),
               Asb + buf * 4096 + ca * 8);
    }
#pragma unroll
    for (int c = 0; c < 4; ++c) {
      int cb2 = c * 256 + tid, row = cb2 >> 3, ks = cb2 & 7;
      gl_lds16(Bb + (size_t)row * K + k0 + ((ks ^ (row & 7)) << 3),
               Bsb + buf * 8192 + cb2 * 8);
    }
  };

  // prologue: stage tiles 0 and 1; wait only for tile 0 (6 oldest of 12)
  stage(0, 0);
  if (nk > 1) {
    stage(1, 64);
    asm volatile("s_waitcnt vmcnt(6)" ::: "memory");
  } else {
    asm volatile("s_waitcnt vmcnt(0)" ::: "memory");
  }
  __builtin_amdgcn_s_barrier();

  int cur = 0;
  for (int kt = 0; kt < nk; ++kt) {
    const char* As = (const char*)(Asb + cur * 4096);
    const char* Bs = (const char*)(Bsb + cur * 8192);
    bf16x8 av[2][2], bv[4][2];
#pragma unroll
    for (int i = 0; i < 2; ++i)
#pragma unroll
      for (int kk = 0; kk < 2; ++kk) {
        int row = wr * 32 + i * 16 + lr;
        av[i][kk] = *(const bf16x8*)(As +
            ((row * 128 + kk * 64 + lg * 16) ^ ((lr & 7) << 4)));
      }
#pragma unroll
    for (int j = 0; j < 4; ++j)
#pragma unroll
      for (int kk = 0; kk < 2; ++kk) {
        int row = wc * 64 + j * 16 + lr;
        bv[j][kk] = *(const bf16x8*)(Bs +
            ((row * 128 + kk * 64 + lg * 16) ^ ((lr & 7) << 4)));
      }
#pragma unroll
    for (int kk = 0; kk < 2; ++kk)
#pragma unroll
      for (int i = 0; i < 2; ++i)
#pragma unroll
        for (int j = 0; j < 4; ++j)
          acc[i][j] = __builtin_amdgcn_mfma_f32_16x16x32_bf16(av[i][kk], bv[j][kk],
                                                              acc[i][j], 0, 0, 0);
    if (kt + 1 < nk) {
      __builtin_amdgcn_s_barrier();        // all waves finished reading buf cur
      if (kt + 2 < nk) {
        stage(cur, (kt + 2) << 6);         // refill buf cur; stays in flight next phase
        asm volatile("s_waitcnt vmcnt(6)" ::: "memory");   // tile kt+1 (oldest 6) landed
      } else {
        asm volatile("s_waitcnt vmcnt(0)" ::: "memory");   // tail: tile kt+1 landed
      }
      __builtin_amdgcn_s_barrier();
    }
    cur ^= 1;
  }

  if (MODE == 0) {
#pragma unroll
    for (int i = 0; i < 2; ++i) {
      int row = m0 + wr * 32 + i * 16 + lg * 4;
#pragma unroll
      for (int j = 0; j < 4; ++j) {
        int col = n0 + wc * 64 + j * 16 + lr;
#pragma unroll
        for (int r = 0; r < 4; ++r)
          Cf[(size_t)(row + r) * N + col] = acc[i][j][r];
      }
    }
    return;
  }
  // MODE 1 fused epilogue
  if (n0 >= 3072) {
#pragma unroll
    for (int i = 0; i < 2; ++i) {
      int row = m0 + wr * 32 + i * 16 + lg * 4;
#pragma unroll
      for (int j = 0; j < 4; ++j) {
        int col = n0 + wc * 64 + j * 16 + lr;
#pragma unroll
        for (int r = 0; r < 4; ++r) {
          float z = acc[i][j][r];
          float sv = z / (1.0f + expf(-z));
          Cg[(size_t)(row + r) * 2048 + (col - 3072)] = (__bf16)sv;
        }
      }
    }
    return;
  }
  // qkv section: rope q,k in-register and scatter; v -> vtb
#pragma unroll
  for (int i = 0; i < 2; ++i) {
    int row0 = m0 + wr * 32 + i * 16 + lg * 4;
#pragma unroll
    for (int j = 0; j < 4; ++j) {
      int cb = n0 + wc * 64 + j * 16;            // frag base col (wave-uniform)
      int g = cb / 768, cm = cb % 768;
      int dbase = (cm < 512) ? (cm & 127) : (cm < 640) ? (cm - 512) : (cm - 640);
      int d = dbase + lr;
      float ov[4];
      if (cm < 640) {                            // rope (q or k)
#pragma unroll
        for (int r = 0; r < 4; ++r) {
          float z = acc[i][j][r];
          float pz = __shfl_xor(z, 1, 64);       // pair partner (col parity == lr parity)
          int t = row0 + r;
          float cc = cosb[t * 64 + (d >> 1)];
          float ss = sinb[t * 64 + (d >> 1)];
          ov[r] = (lr & 1) ? (pz * ss + z * cc) : (z * cc - pz * ss);
        }
      } else {
#pragma unroll
        for (int r = 0; r < 4; ++r) ov[r] = acc[i][j][r];
      }
      if (cm < 512) {                            // q -> qb[h][t][d]
        int hh = g * 4 + (cm >> 7);
#pragma unroll
        for (int r = 0; r < 4; ++r)
          qb[((size_t)hh * T_SEQ + row0 + r) * DH + d] = (__bf16)ov[r];
      } else if (cm < 640) {                     // k -> kb[g][t][d] and ktb[g][d][t]
        bf16x4 kv;
#pragma unroll
        for (int r = 0; r < 4; ++r) {
          kv[r] = (__bf16)ov[r];
          kb[((size_t)g * T_SEQ + row0 + r) * DH + d] = kv[r];
        }
        *(bf16x4*)(ktb + ((size_t)g * DH + d) * T_SEQ + row0) = kv;
      } else {                                   // v -> vtb[g][d][t]
        bf16x4 vv;
#pragma unroll
        for (int r = 0; r < 4; ++r) vv[r] = (__bf16)ov[r];
        *(bf16x4*)(vtb + ((size_t)g * DH + d) * T_SEQ + row0) = vv;
      }
    }
  }
}

extern "C" void kernel_launch(void* const* d_in, const int* in_sizes, int n_in,
                              void* d_out, int out_size, void* d_ws, size_t ws_size,
                              hipStream_t stream) {
  const float* x    = (const float*)d_in[0];
  const float* cosb = (const float*)d_in[1];
  const float* sinb = (const float*)d_in[2];
  // d_in[3] = mask (268MB) -- computed analytically, never read
  const float* Wr   = (const float*)d_in[4];
  const float* Wg   = (const float*)d_in[5];
  const float* Wp   = (const float*)d_in[6];

  char* ws = (char*)d_ws;
  size_t off = 0;
  auto alloc = [&](size_t bytes) { void* p = ws + off; off += (bytes + 255) & ~(size_t)255; return p; };
  __bf16* xb     = (__bf16*)alloc((size_t)CDIM * CDIM * 2);          // 8MB
  __bf16* wtb    = (__bf16*)alloc((size_t)5120 * CDIM * 2);          // 20MB (W_reten^T|W_gate^T)
  __bf16* wpb    = (__bf16*)alloc((size_t)CDIM * CDIM * 2);          // 8MB
  __bf16* qb     = (__bf16*)alloc((size_t)NH * T_SEQ * DH * 2);      // 8MB
  __bf16* kbp    = (__bf16*)alloc((size_t)NG * T_SEQ * DH * 2);      // 2MB
  __bf16* vtb    = (__bf16*)alloc((size_t)NG * DH * T_SEQ * 2);      // 2MB
  __bf16* ktb    = (__bf16*)alloc((size_t)NG * DH * T_SEQ * 2);      // 2MB
  __bf16* gateb  = (__bf16*)alloc((size_t)CDIM * CDIM * 2);          // 8MB
  __bf16* Stb    = (__bf16*)alloc((size_t)NH * NCHUNK * 128 * 128 * 2); // 16MB
  __bf16* ynormb = (__bf16*)alloc((size_t)T_SEQ * CDIM * 2);         // 8MB

  // 1) preprocess: cast x + transpose/cast all weights
  pre_kernel<<<5632, 256, 0, stream>>>(x, Wr, Wg, Wp, xb, wtb, wpb);
  // 2) fused: x @ [W_reten | W_gate] with in-epilogue RoPE/scatter/transpose + silu gate
  gemm_gl_kernel<1><<<dim3(32, 40), 256, 0, stream>>>(
      xb, wtb, nullptr, gateb, cosb, sinb, qb, kbp, vtb, ktb, 2048, 5120, 2048);
  // 3) fused per-chunk decayed KV outer products + state scan -> St bf16
  uscan_kernel<<<256, 256, 0, stream>>>(vtb, ktb, Stb);
  // 4) attention (intra tile + q@S_c) + fused RMS-norm + gate -> ynorm bf16 [T][C]
  attn2_kernel<<<NH * NCHUNK, 256, 0, stream>>>(qb, kbp, vtb, Stb, gateb, ynormb);
  // 5) out = (g*y_norm) @ W_proj
  gemm_gl_kernel<0><<<dim3(32, 16), 256, 0, stream>>>(
      ynormb, wpb, (float*)d_out, nullptr, nullptr, nullptr, nullptr, nullptr, nullptr, nullptr,
      2048, 2048, 2048);
}